// Round 1
// baseline (211.155 us; speedup 1.0000x reference)
//
#include <hip/hip_runtime.h>

// YOLO loss: preds/targets (N,7,7,30) fp32 -> scalar.
// Memory-bound streaming reduction: 192.7 MB read, roofline ~30 us @ 6.3 TB/s.

#define SGRID 7
#define DDIM 30
#define NCLS 20
#define LAMBDA_NOOBJ 0.5f
#define IOU_EPS 1e-10f

#define CELLS_PER_BLOCK 256
#define THREADS 256

__global__ __launch_bounds__(THREADS) void yolo_loss_main(
    const float* __restrict__ preds, const float* __restrict__ targets,
    float* __restrict__ partials, int n_cells) {
    // 256 cells * 30 floats * 4 B = 30720 B per tensor; total 60 KiB + red.
    __shared__ float sp[CELLS_PER_BLOCK * DDIM];
    __shared__ float st[CELLS_PER_BLOCK * DDIM];
    __shared__ float red[THREADS / 64];

    const int tid = threadIdx.x;
    const int cell0 = blockIdx.x * CELLS_PER_BLOCK;
    const long long base_f = (long long)cell0 * DDIM;

    // ---- Stage: coalesced float4 loads (block base is 16B-aligned:
    // cell0*120 = blockIdx*30720). 1920 float4 per tensor, 256 threads.
    {
        const float4* gp = (const float4*)(preds + base_f);
        const float4* gt = (const float4*)(targets + base_f);
        float4* s4p = (float4*)sp;
        float4* s4t = (float4*)st;
        const long long total_f4 = ((long long)n_cells * DDIM) / 4;
        const long long b4 = base_f / 4;
        const int nf4 = CELLS_PER_BLOCK * DDIM / 4;  // 1920
        for (int i = tid; i < nf4; i += THREADS) {
            if (b4 + i < total_f4) {
                s4p[i] = gp[i];
                s4t[i] = gt[i];
            }
        }
    }
    __syncthreads();

    // ---- Compute this thread's cell from LDS.
    float loss = 0.0f;
    const int cell = cell0 + tid;
    if (cell < n_cells) {
        float pv[DDIM], tv[DDIM];
        {
            const float2* p2 = (const float2*)(sp + tid * DDIM);  // 8B-aligned
            const float2* t2 = (const float2*)(st + tid * DDIM);
#pragma unroll
            for (int i = 0; i < DDIM / 2; ++i) {
                ((float2*)pv)[i] = p2[i];
                ((float2*)tv)[i] = t2[i];
            }
        }

        // IoU per box (center format).
        float iou0, iou1;
#pragma unroll
        for (int b = 0; b < 2; ++b) {
            const float x1 = pv[b * 5 + 0], y1 = pv[b * 5 + 1];
            const float w1 = pv[b * 5 + 2], h1 = pv[b * 5 + 3];
            const float x2 = tv[b * 5 + 0], y2 = tv[b * 5 + 1];
            const float w2 = tv[b * 5 + 2], h2 = tv[b * 5 + 3];
            float iw = fminf(x1 + 0.5f * w1, x2 + 0.5f * w2) -
                       fmaxf(x1 - 0.5f * w1, x2 - 0.5f * w2);
            iw = fmaxf(iw, 0.0f);
            float ih = fminf(y1 + 0.5f * h1, y2 + 0.5f * h2) -
                       fmaxf(y1 - 0.5f * h1, y2 - 0.5f * h2);
            ih = fmaxf(ih, 0.0f);
            const float inter = iw * ih;
            const float uni = w1 * h1 + w2 * h2 - inter;
            const float iou = inter / (uni + IOU_EPS);
            if (b == 0) iou0 = iou; else iou1 = iou;
        }

        // argmax ties -> first index (box 0).
        const bool sel1 = iou1 > iou0;

        // coord loss (selected box x,y), gated by has_obj = targets[...,4] > 0.
        {
            const float px = sel1 ? pv[5] : pv[0];
            const float py = sel1 ? pv[6] : pv[1];
            const float tx = sel1 ? tv[5] : tv[0];
            const float ty = sel1 ? tv[6] : tv[1];
            const float dx = px - tx, dy = py - ty;
            if (tv[4] > 0.0f) loss += dx * dx + dy * dy;
        }

        // class SSE + running argmax of target class (ties -> first);
        // track pc_gt by value to avoid dynamic register indexing.
        float gt_val = tv[10];
        float pc_gt = pv[10];
#pragma unroll
        for (int j = 0; j < NCLS; ++j) {
            const float pc = pv[10 + j], tc = tv[10 + j];
            const float d = pc - tc;
            loss += d * d;
            const bool gm = tc > gt_val;
            gt_val = gm ? tc : gt_val;
            pc_gt = gm ? pc : pc_gt;
        }

        // conf loss: w_b * (iou_b * pc_gt - iou_b)^2 = w_b * iou_b^2 * (pc_gt-1)^2
        const float c = pc_gt - 1.0f;
        const float d0 = iou0 * c, d1 = iou1 * c;
        const float w0 = sel1 ? LAMBDA_NOOBJ : 1.0f;
        const float w1 = sel1 ? 1.0f : LAMBDA_NOOBJ;
        loss += w0 * d0 * d0 + w1 * d1 * d1;
    }

    // ---- Block reduction: wave shuffle tree, then cross-wave via LDS.
#pragma unroll
    for (int off = 32; off > 0; off >>= 1) loss += __shfl_down(loss, off, 64);
    if ((tid & 63) == 0) red[tid >> 6] = loss;
    __syncthreads();
    if (tid == 0) {
        float s = 0.0f;
#pragma unroll
        for (int w = 0; w < THREADS / 64; ++w) s += red[w];
        partials[blockIdx.x] = s;
    }
}

__global__ __launch_bounds__(THREADS) void yolo_loss_reduce(
    const float* __restrict__ partials, int n, float inv_n,
    float* __restrict__ out) {
    __shared__ float red[THREADS / 64];
    float v = 0.0f;
    for (int i = threadIdx.x; i < n; i += THREADS) v += partials[i];
#pragma unroll
    for (int off = 32; off > 0; off >>= 1) v += __shfl_down(v, off, 64);
    if ((threadIdx.x & 63) == 0) red[threadIdx.x >> 6] = v;
    __syncthreads();
    if (threadIdx.x == 0) {
        float s = 0.0f;
#pragma unroll
        for (int w = 0; w < THREADS / 64; ++w) s += red[w];
        out[0] = s * inv_n;
    }
}

extern "C" void kernel_launch(void* const* d_in, const int* in_sizes, int n_in,
                              void* d_out, int out_size, void* d_ws, size_t ws_size,
                              hipStream_t stream) {
    const float* preds = (const float*)d_in[0];
    const float* targets = (const float*)d_in[1];
    float* out = (float*)d_out;

    const int total = in_sizes[0];                        // N*S*S*D
    const int n_cells = total / DDIM;                     // N*S*S
    const int N = total / (SGRID * SGRID * DDIM);         // 16384
    const int nblocks = (n_cells + CELLS_PER_BLOCK - 1) / CELLS_PER_BLOCK;

    float* partials = (float*)d_ws;  // nblocks floats; fully written before read

    yolo_loss_main<<<nblocks, THREADS, 0, stream>>>(preds, targets, partials, n_cells);
    yolo_loss_reduce<<<1, THREADS, 0, stream>>>(partials, nblocks, 1.0f / (float)N, out);
}

// Round 2
// 205.339 us; speedup vs baseline: 1.0283x; 1.0283x over previous
//
#include <hip/hip_runtime.h>

// YOLO loss: preds/targets (N,7,7,30) fp32 -> scalar.
// Memory-bound streaming reduction: 192.7 MB read, roofline ~30 us @ 6.3 TB/s.
// R1: async global->LDS staging (global_load_lds width=16) to fix the
// Little's-law latency bound seen in R0 (76 us @ 16% HBM, VALUBusy 7%).

#define SGRID 7
#define DDIM 30
#define NCLS 20
#define LAMBDA_NOOBJ 0.5f
#define IOU_EPS 1e-10f

#define CELLS_PER_BLOCK 256
#define THREADS 256

// Async 16B global->LDS copy: lds dest must be wave-uniform base + lane*16,
// which our linear i = tid + k*THREADS mapping satisfies.
#define GLOAD_LDS16(gp, lp)                                        \
    __builtin_amdgcn_global_load_lds(                              \
        (const __attribute__((address_space(1))) void*)(gp),       \
        (__attribute__((address_space(3))) void*)(lp), 16, 0, 0)

__global__ __launch_bounds__(THREADS) void yolo_loss_main(
    const float* __restrict__ preds, const float* __restrict__ targets,
    float* __restrict__ partials, int n_cells) {
    // 256 cells * 30 floats * 4 B = 30720 B per tensor (60 KiB total ->
    // 2 blocks/CU, 8 waves/CU; each wave keeps 30 KiB of async loads in
    // flight, ~240 KiB/CU >> the ~10 KiB Little's-law requirement).
    __shared__ float sp[CELLS_PER_BLOCK * DDIM];
    __shared__ float st[CELLS_PER_BLOCK * DDIM];
    __shared__ float red[THREADS / 64];

    const int tid = threadIdx.x;
    const int cell0 = blockIdx.x * CELLS_PER_BLOCK;
    const long long base_f = (long long)cell0 * DDIM;

    // ---- Stage: async direct-to-LDS, 16B per lane per issue, no VGPR
    // round-trip. nf4 = 1920 float4 per tensor; 256 threads -> 7.5 passes
    // (last pass half-active: wave-uniform branch, lanes stay contiguous).
    {
        const float4* gp = (const float4*)(preds + base_f);
        const float4* gt = (const float4*)(targets + base_f);
        const int nf4 = CELLS_PER_BLOCK * DDIM / 4;  // 1920
#pragma unroll
        for (int k = 0; k < (nf4 + THREADS - 1) / THREADS; ++k) {
            const int i = tid + k * THREADS;
            if (i < nf4) {
                GLOAD_LDS16(gp + i, sp + i * 4);
                GLOAD_LDS16(gt + i, st + i * 4);
            }
        }
    }
    __syncthreads();  // emits s_waitcnt vmcnt(0) drain + barrier

    // ---- Compute this thread's cell from LDS.
    float loss = 0.0f;
    const int cell = cell0 + tid;
    if (cell < n_cells) {
        float pv[DDIM], tv[DDIM];
        {
            const float2* p2 = (const float2*)(sp + tid * DDIM);  // 8B-aligned
            const float2* t2 = (const float2*)(st + tid * DDIM);
#pragma unroll
            for (int i = 0; i < DDIM / 2; ++i) {
                ((float2*)pv)[i] = p2[i];
                ((float2*)tv)[i] = t2[i];
            }
        }

        // IoU per box (center format).
        float iou0, iou1;
#pragma unroll
        for (int b = 0; b < 2; ++b) {
            const float x1 = pv[b * 5 + 0], y1 = pv[b * 5 + 1];
            const float w1 = pv[b * 5 + 2], h1 = pv[b * 5 + 3];
            const float x2 = tv[b * 5 + 0], y2 = tv[b * 5 + 1];
            const float w2 = tv[b * 5 + 2], h2 = tv[b * 5 + 3];
            float iw = fminf(x1 + 0.5f * w1, x2 + 0.5f * w2) -
                       fmaxf(x1 - 0.5f * w1, x2 - 0.5f * w2);
            iw = fmaxf(iw, 0.0f);
            float ih = fminf(y1 + 0.5f * h1, y2 + 0.5f * h2) -
                       fmaxf(y1 - 0.5f * h1, y2 - 0.5f * h2);
            ih = fmaxf(ih, 0.0f);
            const float inter = iw * ih;
            const float uni = w1 * h1 + w2 * h2 - inter;
            const float iou = inter / (uni + IOU_EPS);
            if (b == 0) iou0 = iou; else iou1 = iou;
        }

        // argmax ties -> first index (box 0).
        const bool sel1 = iou1 > iou0;

        // coord loss (selected box x,y), gated by has_obj = targets[...,4] > 0.
        {
            const float px = sel1 ? pv[5] : pv[0];
            const float py = sel1 ? pv[6] : pv[1];
            const float tx = sel1 ? tv[5] : tv[0];
            const float ty = sel1 ? tv[6] : tv[1];
            const float dx = px - tx, dy = py - ty;
            if (tv[4] > 0.0f) loss += dx * dx + dy * dy;
        }

        // class SSE + running argmax of target class (ties -> first);
        // track pc_gt by value to avoid dynamic register indexing.
        float gt_val = tv[10];
        float pc_gt = pv[10];
#pragma unroll
        for (int j = 0; j < NCLS; ++j) {
            const float pc = pv[10 + j], tc = tv[10 + j];
            const float d = pc - tc;
            loss += d * d;
            const bool gm = tc > gt_val;
            gt_val = gm ? tc : gt_val;
            pc_gt = gm ? pc : pc_gt;
        }

        // conf loss: w_b * (iou_b * pc_gt - iou_b)^2 = w_b * iou_b^2 * (pc_gt-1)^2
        const float c = pc_gt - 1.0f;
        const float d0 = iou0 * c, d1 = iou1 * c;
        const float w0 = sel1 ? LAMBDA_NOOBJ : 1.0f;
        const float w1 = sel1 ? 1.0f : LAMBDA_NOOBJ;
        loss += w0 * d0 * d0 + w1 * d1 * d1;
    }

    // ---- Block reduction: wave shuffle tree, then cross-wave via LDS.
#pragma unroll
    for (int off = 32; off > 0; off >>= 1) loss += __shfl_down(loss, off, 64);
    if ((tid & 63) == 0) red[tid >> 6] = loss;
    __syncthreads();
    if (tid == 0) {
        float s = 0.0f;
#pragma unroll
        for (int w = 0; w < THREADS / 64; ++w) s += red[w];
        partials[blockIdx.x] = s;
    }
}

#define RTHREADS 1024
__global__ __launch_bounds__(RTHREADS) void yolo_loss_reduce(
    const float* __restrict__ partials, int n, float inv_n,
    float* __restrict__ out) {
    __shared__ float red[RTHREADS / 64];
    float v = 0.0f;
    for (int i = threadIdx.x; i < n; i += RTHREADS) v += partials[i];
#pragma unroll
    for (int off = 32; off > 0; off >>= 1) v += __shfl_down(v, off, 64);
    if ((threadIdx.x & 63) == 0) red[threadIdx.x >> 6] = v;
    __syncthreads();
    if (threadIdx.x == 0) {
        float s = 0.0f;
#pragma unroll
        for (int w = 0; w < RTHREADS / 64; ++w) s += red[w];
        out[0] = s * inv_n;
    }
}

extern "C" void kernel_launch(void* const* d_in, const int* in_sizes, int n_in,
                              void* d_out, int out_size, void* d_ws, size_t ws_size,
                              hipStream_t stream) {
    const float* preds = (const float*)d_in[0];
    const float* targets = (const float*)d_in[1];
    float* out = (float*)d_out;

    const int total = in_sizes[0];                        // N*S*S*D
    const int n_cells = total / DDIM;                     // N*S*S
    const int N = total / (SGRID * SGRID * DDIM);         // 16384
    const int nblocks = (n_cells + CELLS_PER_BLOCK - 1) / CELLS_PER_BLOCK;

    float* partials = (float*)d_ws;  // nblocks floats; fully written before read

    yolo_loss_main<<<nblocks, THREADS, 0, stream>>>(preds, targets, partials, n_cells);
    yolo_loss_reduce<<<1, RTHREADS, 0, stream>>>(partials, nblocks, 1.0f / (float)N, out);
}